// Round 6
// baseline (280.997 us; speedup 1.0000x reference)
//
#include <hip/hip_runtime.h>
#include <hip/hip_bf16.h>

// Problem constants
#define B_    8
#define F_    16
#define NP_   196
#define SEQ_  3137        // 1 + F_*NP_
#define H_    8
#define DH_   64
#define BH_   64          // B_*H_
#define M_    25096       // B_*SEQ_
#define MPAD_ 25216       // storage pad (197*128)
#define DIM_  512
#define NQKV_ 1536

typedef _Float16 half8_t __attribute__((ext_vector_type(8)));
typedef _Float16 half4_t __attribute__((ext_vector_type(4)));
typedef float f32x4 __attribute__((ext_vector_type(4)));

// workspace byte offsets
#define XH_OFF     ((size_t)0)                    // [MPAD_][512] f16   25,821,184
#define WQKVT_OFF  ((size_t)25821184)             // [1536][512] f16     1,572,864
#define WOUTT_OFF  ((size_t)27394048)             // [512][512]  f16       524,288
#define QH_OFF     ((size_t)27918336)             // [64][3137][64] f16 25,698,304
#define KH_OFF     ((size_t)53616640)
#define VH_OFF     ((size_t)79314944)
#define ATTNH_OFF  ((size_t)105013248)            // [MPAD_][512] f16   25,821,184

__device__ __forceinline__ void load_lds16(const _Float16* g, _Float16* l) {
  __builtin_amdgcn_global_load_lds(
      (const __attribute__((address_space(1))) void*)g,
      (__attribute__((address_space(3))) void*)l, 16, 0, 0);
}

// bijective XCD-chunk swizzle (m204)
__device__ __forceinline__ int xcd_swz(int orig, int nwg) {
  int q = nwg >> 3, r = nwg & 7;
  int x = orig & 7, j = orig >> 3;
  return (x < r ? x * (q + 1) : r * (q + 1) + (x - r) * q) + j;
}

// ---------------------------------------------------------------------------
// conversion kernels
// ---------------------------------------------------------------------------
__global__ __launch_bounds__(256) void convert_x_kernel(
    const float* __restrict__ x, _Float16* __restrict__ xh) {
  const size_t n8 = (size_t)M_ * DIM_ / 8;
  for (size_t i = (size_t)blockIdx.x * blockDim.x + threadIdx.x; i < n8;
       i += (size_t)gridDim.x * blockDim.x) {
    float4 a = ((const float4*)x)[2 * i];
    float4 b = ((const float4*)x)[2 * i + 1];
    half8_t h;
    h[0] = (_Float16)a.x; h[1] = (_Float16)a.y; h[2] = (_Float16)a.z; h[3] = (_Float16)a.w;
    h[4] = (_Float16)b.x; h[5] = (_Float16)b.y; h[6] = (_Float16)b.z; h[7] = (_Float16)b.w;
    ((half8_t*)xh)[i] = h;
  }
}

// in [R][C] fp32 -> out [C][R] fp16  (R,C multiples of 32)
__global__ __launch_bounds__(256) void transpose_conv_kernel(
    const float* __restrict__ in, _Float16* __restrict__ out, int R, int C) {
  __shared__ float tile[32][33];
  const int r0 = blockIdx.x * 32, c0 = blockIdx.y * 32;
  const int lr = threadIdx.x >> 5, lc = threadIdx.x & 31;
#pragma unroll
  for (int p = 0; p < 4; ++p) {
    int r = p * 8 + lr;
    tile[r][lc] = in[(size_t)(r0 + r) * C + c0 + lc];
  }
  __syncthreads();
#pragma unroll
  for (int p = 0; p < 4; ++p) {
    int rr = p * 8 + lr;
    out[(size_t)(c0 + rr) * R + r0 + lc] = (_Float16)tile[lc][rr];
  }
}

// ---------------------------------------------------------------------------
// 256x256 tile, BK=32, 512 threads (8 waves 2x4), 4-deep circular LDS
// (stage 3 tiles ahead), counted vmcnt(8) at tile boundaries (T3+T4),
// raw s_barrier, setprio around MFMA clusters (T5).
// LDS rows = 32 f16 = 64B; slot swizzle s ^ ((row>>1)&3) -> 2-way (free).
// global_load_lds dest linear, source col pre-swizzled (rule #21).
// ---------------------------------------------------------------------------
#define TILE_HALF 8192   // f16 elems per (256x32) tile buffer

// stage one 256x32 f16 tile: 2 x 16B loads per thread
__device__ __forceinline__ void stage_mat(
    const _Float16* __restrict__ src, int row0, int k0, int maxR,
    _Float16* lds, int tid) {
  const int w = tid >> 6;
#pragma unroll
  for (int j = 0; j < 2; ++j) {
    int r = (tid >> 2) + j * 128;
    int slot = (tid & 3) ^ ((r >> 1) & 3);
    int gr = min(row0 + r, maxR);
    load_lds16(src + (size_t)gr * DIM_ + k0 + slot * 8,
               lds + j * 4096 + w * 512);
  }
}

__device__ __forceinline__ half8_t fragld(const _Float16* buf, int r, int g) {
  return *(const half8_t*)(buf + r * 32 + (((g ^ (r >> 1)) & 3) << 3));
}

__device__ __forceinline__ void gemm256_k32(
    const _Float16* __restrict__ A, const _Float16* __restrict__ Bt,
    int m0, int n0, int maxA, int maxB, _Float16* As, _Float16* Bs,
    f32x4 acc[8][4]) {
  const int tid = threadIdx.x;
  const int w = tid >> 6, lane = tid & 63;
  const int wr = w >> 2, wc = w & 3;
  const int lrow = lane & 15, g = lane >> 4;

  // prologue: stage tiles 0,1,2 (order A0,B0,A1,B1,A2,B2 = 12 loads/thread)
  stage_mat(A, m0, 0, maxA, As, tid);
  stage_mat(Bt, n0, 0, maxB, Bs, tid);
  stage_mat(A, m0, 32, maxA, As + TILE_HALF, tid);
  stage_mat(Bt, n0, 32, maxB, Bs + TILE_HALF, tid);
  stage_mat(A, m0, 64, maxA, As + 2 * TILE_HALF, tid);
  stage_mat(Bt, n0, 64, maxB, Bs + 2 * TILE_HALF, tid);
  asm volatile("s_waitcnt vmcnt(8)" ::: "memory");  // tile 0 landed
  __builtin_amdgcn_s_barrier();

  for (int t = 0; t < 16; ++t) {
    const _Float16* Ab = As + (t & 3) * TILE_HALF;
    const _Float16* Bb = Bs + (t & 3) * TILE_HALF;
    _Float16* Aw = As + ((t + 3) & 3) * TILE_HALF;
    _Float16* Bw = Bs + ((t + 3) & 3) * TILE_HALF;
    const bool pf = t < 13;  // stage tile t+3

    // ---- phase 0: stage A(t+3); read A m0-3 + all B frags; MFMA m0-3 ----
    if (pf) stage_mat(A, m0, (t + 3) * 32, maxA, Aw, tid);
    half8_t a[4], b[4];
#pragma unroll
    for (int n = 0; n < 4; ++n) b[n] = fragld(Bb, wc * 64 + n * 16 + lrow, g);
#pragma unroll
    for (int m = 0; m < 4; ++m) a[m] = fragld(Ab, wr * 128 + m * 16 + lrow, g);
    __builtin_amdgcn_s_barrier();
    __builtin_amdgcn_s_setprio(1);
#pragma unroll
    for (int m = 0; m < 4; ++m)
#pragma unroll
      for (int n = 0; n < 4; ++n)
        acc[m][n] = __builtin_amdgcn_mfma_f32_16x16x32_f16(a[m], b[n], acc[m][n], 0, 0, 0);
    __builtin_amdgcn_s_setprio(0);
    __builtin_amdgcn_s_barrier();

    // ---- phase 1: stage B(t+3); read A m4-7; MFMA m4-7 ----
    if (pf) stage_mat(Bt, n0, (t + 3) * 32, maxB, Bw, tid);
    half8_t a2[4];
#pragma unroll
    for (int m = 0; m < 4; ++m)
      a2[m] = fragld(Ab, wr * 128 + 64 + m * 16 + lrow, g);
    __builtin_amdgcn_s_barrier();
    __builtin_amdgcn_s_setprio(1);
#pragma unroll
    for (int m = 0; m < 4; ++m)
#pragma unroll
      for (int n = 0; n < 4; ++n)
        acc[4 + m][n] = __builtin_amdgcn_mfma_f32_16x16x32_f16(a2[m], b[n], acc[4 + m][n], 0, 0, 0);
    __builtin_amdgcn_s_setprio(0);

    // ---- boundary: counted wait (never 0 until the tail), then barrier ----
    if (t < 13)       asm volatile("s_waitcnt vmcnt(8)" ::: "memory");
    else if (t == 13) asm volatile("s_waitcnt vmcnt(4)" ::: "memory");
    else if (t == 14) asm volatile("s_waitcnt vmcnt(0)" ::: "memory");
    if (t < 15) __builtin_amdgcn_s_barrier();
  }
}

// ---------------------------------------------------------------------------
// K1: qkv = xh @ WqkvT^T, scatter into qh/kh/vh [bh][t][64] f16, q scaled.
// ---------------------------------------------------------------------------
__global__ __launch_bounds__(512, 2) void qkv_gemm_kernel(
    const _Float16* __restrict__ xh, const _Float16* __restrict__ wqkvT,
    _Float16* __restrict__ qh, _Float16* __restrict__ kh, _Float16* __restrict__ vh) {
  __shared__ _Float16 As[4 * TILE_HALF];
  __shared__ _Float16 Bs[4 * TILE_HALF];
  const int nwg = 99 * 6;
  const int lin = xcd_swz(blockIdx.x, nwg);
  const int mb = lin / 6, nb = lin - mb * 6;
  const int m0 = mb * 256, n0 = nb * 256;

  f32x4 acc[8][4];
#pragma unroll
  for (int m = 0; m < 8; ++m)
#pragma unroll
    for (int n = 0; n < 4; ++n) acc[m][n] = (f32x4)0.f;

  gemm256_k32(xh, wqkvT, m0, n0, M_ - 1, NQKV_ - 1, As, Bs, acc);

  const int tid = threadIdx.x;
  const int w = tid >> 6, lane = tid & 63;
  const int wr = w >> 2, wc = w & 3;
  const int lrow = lane & 15, g = lane >> 4;
#pragma unroll
  for (int n = 0; n < 4; ++n) {
    const int gcb = n0 + wc * 64 + n * 16;
    const int which = gcb >> 9;
    const int h = (gcb >> 6) & 7;
    const int dbase = (gcb & 63) + lrow;
    const float scale = (which == 0) ? 0.125f : 1.0f;
    _Float16* dst = (which == 0) ? qh : (which == 1) ? kh : vh;
#pragma unroll
    for (int m = 0; m < 8; ++m)
#pragma unroll
      for (int j = 0; j < 4; ++j) {
        int grow = m0 + wr * 128 + m * 16 + g * 4 + j;
        if (grow < M_) {
          int b = grow / SEQ_;
          int t = grow - b * SEQ_;
          dst[((size_t)(b * H_ + h) * SEQ_ + t) * DH_ + dbase] =
              (_Float16)(acc[m][n][j] * scale);
        }
      }
  }
}

// ---------------------------------------------------------------------------
// K4: out = attnh @ WoutT^T + bout (fp32 out).
// ---------------------------------------------------------------------------
__global__ __launch_bounds__(512, 2) void out_gemm_kernel(
    const _Float16* __restrict__ attnh, const _Float16* __restrict__ woutT,
    const float* __restrict__ bias, float* __restrict__ out) {
  __shared__ _Float16 As[4 * TILE_HALF];
  __shared__ _Float16 Bs[4 * TILE_HALF];
  const int nwg = 99 * 2;
  const int lin = xcd_swz(blockIdx.x, nwg);
  const int mb = lin >> 1, nb = lin & 1;
  const int m0 = mb * 256, n0 = nb * 256;

  f32x4 acc[8][4];
#pragma unroll
  for (int m = 0; m < 8; ++m)
#pragma unroll
    for (int n = 0; n < 4; ++n) acc[m][n] = (f32x4)0.f;

  gemm256_k32(attnh, woutT, m0, n0, M_ - 1, DIM_ - 1, As, Bs, acc);

  const int tid = threadIdx.x;
  const int w = tid >> 6, lane = tid & 63;
  const int wr = w >> 2, wc = w & 3;
  const int lrow = lane & 15, g = lane >> 4;
#pragma unroll
  for (int n = 0; n < 4; ++n) {
    const int gcol = n0 + wc * 64 + n * 16 + lrow;
    const float bv = bias[gcol];
#pragma unroll
    for (int m = 0; m < 8; ++m)
#pragma unroll
      for (int j = 0; j < 4; ++j) {
        int grow = m0 + wr * 128 + m * 16 + g * 4 + j;
        if (grow < M_) out[(size_t)grow * DIM_ + gcol] = acc[m][n][j] + bv;
      }
  }
}

// ---------------------------------------------------------------------------
// K2: CLS attention (fp16 in, fp32 math). One block per (b,h), 1024 threads.
// ---------------------------------------------------------------------------
__global__ __launch_bounds__(1024) void cls_attn_kernel(
    const _Float16* __restrict__ qh, const _Float16* __restrict__ kh,
    const _Float16* __restrict__ vh, _Float16* __restrict__ attnh) {
  const int bh = blockIdx.x;
  const int b = bh >> 3, h = bh & 7;
  const int tid = threadIdx.x;
  __shared__ float qs[64];
  __shared__ float s[SEQ_];
  __shared__ float red[1024];

  if (tid < 64) qs[tid] = (float)qh[(size_t)bh * SEQ_ * DH_ + tid];
  __syncthreads();

  float lmax = -1e30f;
  for (int j = tid; j < SEQ_; j += 1024) {
    const half8_t* kr = (const half8_t*)(kh + ((size_t)bh * SEQ_ + j) * DH_);
    float sc = 0.f;
#pragma unroll
    for (int i = 0; i < 8; ++i) {
      half8_t kk = kr[i];
#pragma unroll
      for (int u = 0; u < 8; ++u) sc += qs[8 * i + u] * (float)kk[u];
    }
    s[j] = sc;
    lmax = fmaxf(lmax, sc);
  }
  red[tid] = lmax; __syncthreads();
  for (int st = 512; st > 0; st >>= 1) {
    if (tid < st) red[tid] = fmaxf(red[tid], red[tid + st]);
    __syncthreads();
  }
  float m = red[0]; __syncthreads();

  float lsum = 0.f;
  for (int j = tid; j < SEQ_; j += 1024) {
    float p = __expf(s[j] - m);
    s[j] = p;
    lsum += p;
  }
  red[tid] = lsum; __syncthreads();
  for (int st = 512; st > 0; st >>= 1) {
    if (tid < st) red[tid] += red[tid + st];
    __syncthreads();
  }
  float l = red[0]; __syncthreads();

  const int d = tid & 63, c = tid >> 6;  // c in 0..15
  float a = 0.f;
  for (int j = c; j < SEQ_; j += 16)
    a += s[j] * (float)vh[((size_t)bh * SEQ_ + j) * DH_ + d];
  red[tid] = a; __syncthreads();
  if (tid < 64) {
    float o = 0.f;
#pragma unroll
    for (int i = 0; i < 16; ++i) o += red[i * 64 + tid];
    attnh[(size_t)(b * SEQ_) * DIM_ + h * DH_ + tid] = (_Float16)(o / l);
  }
}

// ---------------------------------------------------------------------------
// K3: frame attention, MFMA. One block per (bh, frame), 4 waves.
// ---------------------------------------------------------------------------
__global__ __launch_bounds__(256) void frame_attn_kernel(
    const _Float16* __restrict__ qh, const _Float16* __restrict__ kh,
    const _Float16* __restrict__ vh, _Float16* __restrict__ attnh) {
  const int bx = blockIdx.x;
  const int bh = bx >> 4, fi = bx & 15;
  const int b = bh >> 3, h = bh & 7;
  const int tid = threadIdx.x;
  const int w = tid >> 6, lane = tid & 63;
  const int g = lane >> 4, lc = lane & 15;

  __shared__ _Float16 VT[64 * 232];      // V^T [d][key], cols 197..231 zero
  __shared__ _Float16 Pb[4][16 * 232];   // per-wave P [q][key]
  _Float16* Pw = Pb[w];

  const size_t base = (size_t)bh * SEQ_ * DH_;

  for (int item = tid; item < 197 * 8; item += 256) {
    int c8 = item / 197;
    int key = item - c8 * 197;
    int rowtok = (key == 0) ? 0 : fi * NP_ + key;
    half8_t hv = *(const half8_t*)(vh + base + (size_t)rowtok * DH_ + c8 * 8);
#pragma unroll
    for (int u = 0; u < 8; ++u) VT[(c8 * 8 + u) * 232 + key] = hv[u];
  }
  for (int idx = tid; idx < 64 * 35; idx += 256) {
    int d = idx / 35;
    VT[d * 232 + 197 + (idx - d * 35)] = (_Float16)0.f;
  }
#pragma unroll
  for (int z = 0; z < 4; ++z) {
    int idx = z * 64 + lane;
    Pw[(idx >> 4) * 232 + 208 + (idx & 15)] = (_Float16)0.f;
  }
  __syncthreads();

  const f32x4 zero4 = (f32x4)0.f;

  for (int qt = w; qt < 13; qt += 4) {
    int qq = qt * 16 + lc;
    int qtok = 1 + fi * NP_ + min(qq, NP_ - 1);
    const _Float16* qp = qh + base + (size_t)qtok * DH_ + g * 8;
    half8_t qb0 = *(const half8_t*)(qp);
    half8_t qb1 = *(const half8_t*)(qp + 32);

    f32x4 st[13];
#pragma unroll
    for (int t = 0; t < 13; ++t) {
      int key = t * 16 + lc;
      int rowtok = (key == 0) ? 0 : fi * NP_ + min(key, NP_);
      const _Float16* kp = kh + base + (size_t)rowtok * DH_ + g * 8;
      half8_t ka0 = *(const half8_t*)(kp);
      half8_t ka1 = *(const half8_t*)(kp + 32);
      st[t] = __builtin_amdgcn_mfma_f32_16x16x32_f16(ka0, qb0, zero4, 0, 0, 0);
      st[t] = __builtin_amdgcn_mfma_f32_16x16x32_f16(ka1, qb1, st[t], 0, 0, 0);
    }

    float mx = -1e30f;
#pragma unroll
    for (int t = 0; t < 13; ++t)
#pragma unroll
      for (int j = 0; j < 4; ++j) {
        int key = t * 16 + g * 4 + j;
        if (key >= 197) st[t][j] = -1e30f;
        mx = fmaxf(mx, st[t][j]);
      }
    mx = fmaxf(mx, __shfl_xor(mx, 16));
    mx = fmaxf(mx, __shfl_xor(mx, 32));
    float l = 0.f;
#pragma unroll
    for (int t = 0; t < 13; ++t)
#pragma unroll
      for (int j = 0; j < 4; ++j) {
        float p = __expf(st[t][j] - mx);
        st[t][j] = p;
        l += p;
      }
    l += __shfl_xor(l, 16);
    l += __shfl_xor(l, 32);
    const float inv = 1.f / l;

#pragma unroll
    for (int t = 0; t < 13; ++t) {
      half4_t hp;
#pragma unroll
      for (int j = 0; j < 4; ++j) hp[j] = (_Float16)(st[t][j] * inv);
      *(half4_t*)(Pw + lc * 232 + t * 16 + g * 4) = hp;
    }

    f32x4 o[4];
#pragma unroll
    for (int dt = 0; dt < 4; ++dt) o[dt] = zero4;
#pragma unroll
    for (int c = 0; c < 7; ++c) {
      half8_t pa = *(const half8_t*)(Pw + lc * 232 + c * 32 + g * 8);
#pragma unroll
      for (int dt = 0; dt < 4; ++dt) {
        half8_t vb = *(const half8_t*)(VT + (dt * 16 + lc) * 232 + c * 32 + g * 8);
        o[dt] = __builtin_amdgcn_mfma_f32_16x16x32_f16(pa, vb, o[dt], 0, 0, 0);
      }
    }

#pragma unroll
    for (int dt = 0; dt < 4; ++dt)
#pragma unroll
      for (int j = 0; j < 4; ++j) {
        int q = qt * 16 + g * 4 + j;
        if (q < NP_) {
          int tok = 1 + fi * NP_ + q;
          attnh[((size_t)(b * SEQ_) + tok) * DIM_ + h * DH_ + dt * 16 + lc] =
              (_Float16)o[dt][j];
        }
      }
  }
}

// ---------------------------------------------------------------------------
extern "C" void kernel_launch(void* const* d_in, const int* in_sizes, int n_in,
                              void* d_out, int out_size, void* d_ws, size_t ws_size,
                              hipStream_t stream) {
  (void)in_sizes; (void)n_in; (void)out_size; (void)ws_size;
  const float* x    = (const float*)d_in[0];
  const float* wqkv = (const float*)d_in[1];
  const float* wout = (const float*)d_in[2];
  const float* bout = (const float*)d_in[3];
  char* ws = (char*)d_ws;
  _Float16* xh    = (_Float16*)(ws + XH_OFF);
  _Float16* wqkvT = (_Float16*)(ws + WQKVT_OFF);
  _Float16* woutT = (_Float16*)(ws + WOUTT_OFF);
  _Float16* qh    = (_Float16*)(ws + QH_OFF);
  _Float16* kh    = (_Float16*)(ws + KH_OFF);
  _Float16* vh    = (_Float16*)(ws + VH_OFF);
  _Float16* attnh = (_Float16*)(ws + ATTNH_OFF);
  float* out = (float*)d_out;

  convert_x_kernel<<<2048, 256, 0, stream>>>(x, xh);
  {
    dim3 g(DIM_ / 32, NQKV_ / 32);
    transpose_conv_kernel<<<g, 256, 0, stream>>>(wqkv, wqkvT, DIM_, NQKV_);
  }
  {
    dim3 g(DIM_ / 32, DIM_ / 32);
    transpose_conv_kernel<<<g, 256, 0, stream>>>(wout, woutT, DIM_, DIM_);
  }

  qkv_gemm_kernel<<<99 * 6, 512, 0, stream>>>(xh, wqkvT, qh, kh, vh);

  cls_attn_kernel<<<BH_, 1024, 0, stream>>>(qh, kh, vh, attnh);
  frame_attn_kernel<<<BH_ * F_, 256, 0, stream>>>(qh, kh, vh, attnh);

  out_gemm_kernel<<<99 * 2, 512, 0, stream>>>(attnh, woutT, bout, out);
}

// Round 7
// 253.766 us; speedup vs baseline: 1.1073x; 1.1073x over previous
//
#include <hip/hip_runtime.h>
#include <hip/hip_bf16.h>

// Problem constants
#define B_    8
#define F_    16
#define NP_   196
#define SEQ_  3137        // 1 + F_*NP_
#define H_    8
#define DH_   64
#define BH_   64          // B_*H_
#define M_    25096       // B_*SEQ_
#define MPAD_ 25216       // storage pad (197*128)
#define DIM_  512
#define NQKV_ 1536

typedef _Float16 half8_t __attribute__((ext_vector_type(8)));
typedef _Float16 half4_t __attribute__((ext_vector_type(4)));
typedef float f32x4 __attribute__((ext_vector_type(4)));

// workspace byte offsets
#define XH_OFF     ((size_t)0)                    // [MPAD_][512] f16   25,821,184
#define WQKVT_OFF  ((size_t)25821184)             // [1536][512] f16     1,572,864
#define WOUTT_OFF  ((size_t)27394048)             // [512][512]  f16       524,288
#define QH_OFF     ((size_t)27918336)             // [64][3137][64] f16 25,698,304
#define KH_OFF     ((size_t)53616640)
#define VH_OFF     ((size_t)79314944)
#define ATTNH_OFF  ((size_t)105013248)            // [MPAD_][512] f16   25,821,184

__device__ __forceinline__ void load_lds16(const _Float16* g, _Float16* l) {
  __builtin_amdgcn_global_load_lds(
      (const __attribute__((address_space(1))) void*)g,
      (__attribute__((address_space(3))) void*)l, 16, 0, 0);
}

// bijective XCD-chunk swizzle (m204)
__device__ __forceinline__ int xcd_swz(int orig, int nwg) {
  int q = nwg >> 3, r = nwg & 7;
  int x = orig & 7, j = orig >> 3;
  return (x < r ? x * (q + 1) : r * (q + 1) + (x - r) * q) + j;
}

// ---------------------------------------------------------------------------
// conversion kernels
// ---------------------------------------------------------------------------
__global__ __launch_bounds__(256) void convert_x_kernel(
    const float* __restrict__ x, _Float16* __restrict__ xh) {
  const size_t n8 = (size_t)M_ * DIM_ / 8;
  for (size_t i = (size_t)blockIdx.x * blockDim.x + threadIdx.x; i < n8;
       i += (size_t)gridDim.x * blockDim.x) {
    float4 a = ((const float4*)x)[2 * i];
    float4 b = ((const float4*)x)[2 * i + 1];
    half8_t h;
    h[0] = (_Float16)a.x; h[1] = (_Float16)a.y; h[2] = (_Float16)a.z; h[3] = (_Float16)a.w;
    h[4] = (_Float16)b.x; h[5] = (_Float16)b.y; h[6] = (_Float16)b.z; h[7] = (_Float16)b.w;
    ((half8_t*)xh)[i] = h;
  }
}

// in [R][C] fp32 -> out [C][R] fp16  (R,C multiples of 32)
__global__ __launch_bounds__(256) void transpose_conv_kernel(
    const float* __restrict__ in, _Float16* __restrict__ out, int R, int C) {
  __shared__ float tile[32][33];
  const int r0 = blockIdx.x * 32, c0 = blockIdx.y * 32;
  const int lr = threadIdx.x >> 5, lc = threadIdx.x & 31;
#pragma unroll
  for (int p = 0; p < 4; ++p) {
    int r = p * 8 + lr;
    tile[r][lc] = in[(size_t)(r0 + r) * C + c0 + lc];
  }
  __syncthreads();
#pragma unroll
  for (int p = 0; p < 4; ++p) {
    int rr = p * 8 + lr;
    out[(size_t)(c0 + rr) * R + r0 + lc] = (_Float16)tile[lc][rr];
  }
}

// ---------------------------------------------------------------------------
// shared f16 MFMA mainloop: 128x128 tile, BK=64, 256 threads (4 waves 2x2).
// (R4 structure — best measured.) LDS XOR-swizzled: linear global_load_lds
// dest + pre-swizzled global source col; frag reads XOR (row&7)<<3.
// ---------------------------------------------------------------------------
__device__ __forceinline__ void gemm_mainloop_f16(
    const _Float16* __restrict__ A, const _Float16* __restrict__ Bt,
    int m0, int n0, _Float16* As, _Float16* Bs, f32x4 acc[4][4]) {
  const int tid = threadIdx.x;
  const int w = tid >> 6, lane = tid & 63;
  const int wr = w >> 1, wc = w & 1;
  const int lrow = lane & 15;
  const int g = lane >> 4;
  const int sw = lane & 7;

  const int srow = lane >> 3;
  const int scol = ((lane & 7) ^ srow) << 3;

  for (int k0 = 0; k0 < DIM_; k0 += 64) {
#pragma unroll
    for (int i = 0; i < 4; ++i) {
      int c = w * 4 + i;
      int r = c * 8 + srow;
      load_lds16(A + (size_t)(m0 + r) * DIM_ + k0 + scol, As + c * 512);
      load_lds16(Bt + (size_t)(n0 + r) * DIM_ + k0 + scol, Bs + c * 512);
    }
    __syncthreads();

#pragma unroll
    for (int kk = 0; kk < 2; ++kk) {
      const int kf = ((kk * 4 + g) ^ sw) << 3;
      half8_t a[4], b[4];
#pragma unroll
      for (int m = 0; m < 4; ++m)
        a[m] = *(const half8_t*)(As + (wr * 64 + m * 16 + lrow) * 64 + kf);
#pragma unroll
      for (int n = 0; n < 4; ++n)
        b[n] = *(const half8_t*)(Bs + (wc * 64 + n * 16 + lrow) * 64 + kf);
#pragma unroll
      for (int m = 0; m < 4; ++m)
#pragma unroll
        for (int n = 0; n < 4; ++n)
          acc[m][n] = __builtin_amdgcn_mfma_f32_16x16x32_f16(a[m], b[n], acc[m][n], 0, 0, 0);
    }
    __syncthreads();
  }
}

// ---------------------------------------------------------------------------
// K1: qkv = xh @ WqkvT^T, scatter into qh/kh/vh [bh][t][64] f16, q scaled.
// Staged coalesced epilogue: per-wave 64x64 f16 tile via LDS (XOR slots),
// re-read as half8 -> 128B contiguous row stores (fixes 1.8x write amp).
// ---------------------------------------------------------------------------
__global__ __launch_bounds__(256) void qkv_gemm_kernel(
    const _Float16* __restrict__ xh, const _Float16* __restrict__ wqkvT,
    _Float16* __restrict__ qh, _Float16* __restrict__ kh, _Float16* __restrict__ vh) {
  __shared__ _Float16 As[128 * 64];
  __shared__ _Float16 Bs[128 * 64];
  const int nwg = 197 * 12;
  const int lin = xcd_swz(blockIdx.x, nwg);
  const int mb = lin / 12, nb = lin - mb * 12;
  const int m0 = mb * 128, n0 = nb * 128;

  f32x4 acc[4][4];
#pragma unroll
  for (int m = 0; m < 4; ++m)
#pragma unroll
    for (int n = 0; n < 4; ++n) acc[m][n] = (f32x4)0.f;

  gemm_mainloop_f16(xh, wqkvT, m0, n0, As, Bs, acc);
  // mainloop ends with __syncthreads(): safe to reuse As/Bs as staging.

  const int tid = threadIdx.x;
  const int w = tid >> 6, lane = tid & 63;
  const int wr = w >> 1, wc = w & 1;
  const int g = lane >> 4, lrow = lane & 15;

  _Float16* stg = (w < 2) ? (As + w * 4096) : (Bs + (w - 2) * 4096);
  const int gcb0 = n0 + wc * 64;            // 64-aligned -> one head chunk
  const int which = gcb0 >> 9;
  const int h = (gcb0 >> 6) & 7;
  const float scale = (which == 0) ? 0.125f : 1.0f;
  _Float16* dst = (which == 0) ? qh : (which == 1) ? kh : vh;

#pragma unroll
  for (int m = 0; m < 4; ++m)
#pragma unroll
    for (int n = 0; n < 4; ++n)
#pragma unroll
      for (int j = 0; j < 4; ++j) {
        int row = m * 16 + g * 4 + j;
        int col = n * 16 + lrow;
        int slot = (col >> 3) ^ (row & 7);
        stg[row * 64 + slot * 8 + (col & 7)] = (_Float16)(acc[m][n][j] * scale);
      }
  asm volatile("s_waitcnt lgkmcnt(0)" ::: "memory");
  __builtin_amdgcn_sched_barrier(0);

  const int rl = lane >> 3, cs = lane & 7;
#pragma unroll
  for (int rr = 0; rr < 8; ++rr) {
    int row = rr * 8 + rl;
    int grow = m0 + wr * 64 + row;
    if (grow < M_) {
      int b = grow / SEQ_;
      int t = grow - b * SEQ_;
      half8_t v = *(const half8_t*)(stg + row * 64 + ((cs ^ (row & 7)) << 3));
      *(half8_t*)(dst + ((size_t)(b * H_ + h) * SEQ_ + t) * DH_ + cs * 8) = v;
    }
  }
}

// ---------------------------------------------------------------------------
// K4: out = attnh @ WoutT^T + bout (fp32 out; 64B-contiguous stores are
// already full cache lines -> direct epilogue).
// ---------------------------------------------------------------------------
__global__ __launch_bounds__(256) void out_gemm_kernel(
    const _Float16* __restrict__ attnh, const _Float16* __restrict__ woutT,
    const float* __restrict__ bias, float* __restrict__ out) {
  __shared__ _Float16 As[128 * 64];
  __shared__ _Float16 Bs[128 * 64];
  const int nwg = 197 * 4;
  const int lin = xcd_swz(blockIdx.x, nwg);
  const int mb = lin >> 2, nb = lin & 3;
  const int m0 = mb * 128, n0 = nb * 128;

  f32x4 acc[4][4];
#pragma unroll
  for (int m = 0; m < 4; ++m)
#pragma unroll
    for (int n = 0; n < 4; ++n) acc[m][n] = (f32x4)0.f;

  gemm_mainloop_f16(attnh, woutT, m0, n0, As, Bs, acc);

  const int tid = threadIdx.x;
  const int w = tid >> 6, lane = tid & 63;
  const int wr = w >> 1, wc = w & 1;
#pragma unroll
  for (int n = 0; n < 4; ++n) {
    const int gcol = n0 + wc * 64 + n * 16 + (lane & 15);
    const float bv = bias[gcol];
#pragma unroll
    for (int m = 0; m < 4; ++m)
#pragma unroll
      for (int j = 0; j < 4; ++j) {
        int grow = m0 + wr * 64 + m * 16 + (lane >> 4) * 4 + j;
        if (grow < M_) out[(size_t)grow * DIM_ + gcol] = acc[m][n][j] + bv;
      }
  }
}

// ---------------------------------------------------------------------------
// K2: CLS attention (fp16 in, fp32 math). One block per (b,h), 1024 threads.
// ---------------------------------------------------------------------------
__global__ __launch_bounds__(1024) void cls_attn_kernel(
    const _Float16* __restrict__ qh, const _Float16* __restrict__ kh,
    const _Float16* __restrict__ vh, _Float16* __restrict__ attnh) {
  const int bh = blockIdx.x;
  const int b = bh >> 3, h = bh & 7;
  const int tid = threadIdx.x;
  __shared__ float qs[64];
  __shared__ float s[SEQ_];
  __shared__ float red[1024];

  if (tid < 64) qs[tid] = (float)qh[(size_t)bh * SEQ_ * DH_ + tid];
  __syncthreads();

  float lmax = -1e30f;
  for (int j = tid; j < SEQ_; j += 1024) {
    const half8_t* kr = (const half8_t*)(kh + ((size_t)bh * SEQ_ + j) * DH_);
    float sc = 0.f;
#pragma unroll
    for (int i = 0; i < 8; ++i) {
      half8_t kk = kr[i];
#pragma unroll
      for (int u = 0; u < 8; ++u) sc += qs[8 * i + u] * (float)kk[u];
    }
    s[j] = sc;
    lmax = fmaxf(lmax, sc);
  }
  red[tid] = lmax; __syncthreads();
  for (int st = 512; st > 0; st >>= 1) {
    if (tid < st) red[tid] = fmaxf(red[tid], red[tid + st]);
    __syncthreads();
  }
  float m = red[0]; __syncthreads();

  float lsum = 0.f;
  for (int j = tid; j < SEQ_; j += 1024) {
    float p = __expf(s[j] - m);
    s[j] = p;
    lsum += p;
  }
  red[tid] = lsum; __syncthreads();
  for (int st = 512; st > 0; st >>= 1) {
    if (tid < st) red[tid] += red[tid + st];
    __syncthreads();
  }
  float l = red[0]; __syncthreads();

  const int d = tid & 63, c = tid >> 6;  // c in 0..15
  float a = 0.f;
  for (int j = c; j < SEQ_; j += 16)
    a += s[j] * (float)vh[((size_t)bh * SEQ_ + j) * DH_ + d];
  red[tid] = a; __syncthreads();
  if (tid < 64) {
    float o = 0.f;
#pragma unroll
    for (int i = 0; i < 16; ++i) o += red[i * 64 + tid];
    attnh[(size_t)(b * SEQ_) * DIM_ + h * DH_ + tid] = (_Float16)(o / l);
  }
}

// ---------------------------------------------------------------------------
// K3: frame attention, MFMA. One block per (bh, frame), 4 waves.
// K-tile fragments hoisted to registers ONCE per wave (was re-read from
// global 3-4x per wave). 26 half8 = 104 VGPR; launch_bounds(256,2).
// ---------------------------------------------------------------------------
__global__ __launch_bounds__(256, 2) void frame_attn_kernel(
    const _Float16* __restrict__ qh, const _Float16* __restrict__ kh,
    const _Float16* __restrict__ vh, _Float16* __restrict__ attnh) {
  const int bx = blockIdx.x;
  const int bh = bx >> 4, fi = bx & 15;
  const int b = bh >> 3, h = bh & 7;
  const int tid = threadIdx.x;
  const int w = tid >> 6, lane = tid & 63;
  const int g = lane >> 4, lc = lane & 15;

  __shared__ _Float16 VT[64 * 232];      // V^T [d][key], cols 197..231 zero
  __shared__ _Float16 Pb[4][16 * 232];   // per-wave P [q][key]
  _Float16* Pw = Pb[w];

  const size_t base = (size_t)bh * SEQ_ * DH_;

  // K fragments -> registers (once per wave)
  half8_t ka0[13], ka1[13];
#pragma unroll
  for (int t = 0; t < 13; ++t) {
    int key = t * 16 + lc;
    int rowtok = (key == 0) ? 0 : fi * NP_ + min(key, NP_);
    const _Float16* kp = kh + base + (size_t)rowtok * DH_ + g * 8;
    ka0[t] = *(const half8_t*)(kp);
    ka1[t] = *(const half8_t*)(kp + 32);
  }

  // stage V^T (transpose-scatter), valid keys 0..196
  for (int item = tid; item < 197 * 8; item += 256) {
    int c8 = item / 197;
    int key = item - c8 * 197;
    int rowtok = (key == 0) ? 0 : fi * NP_ + key;
    half8_t hv = *(const half8_t*)(vh + base + (size_t)rowtok * DH_ + c8 * 8);
#pragma unroll
    for (int u = 0; u < 8; ++u) VT[(c8 * 8 + u) * 232 + key] = hv[u];
  }
  for (int idx = tid; idx < 64 * 35; idx += 256) {
    int d = idx / 35;
    VT[d * 232 + 197 + (idx - d * 35)] = (_Float16)0.f;
  }
#pragma unroll
  for (int z = 0; z < 4; ++z) {
    int idx = z * 64 + lane;
    Pw[(idx >> 4) * 232 + 208 + (idx & 15)] = (_Float16)0.f;
  }
  __syncthreads();

  const f32x4 zero4 = (f32x4)0.f;

  for (int qt = w; qt < 13; qt += 4) {
    int qq = qt * 16 + lc;
    int qtok = 1 + fi * NP_ + min(qq, NP_ - 1);
    const _Float16* qp = qh + base + (size_t)qtok * DH_ + g * 8;
    half8_t qb0 = *(const half8_t*)(qp);
    half8_t qb1 = *(const half8_t*)(qp + 32);

    f32x4 st[13];
#pragma unroll
    for (int t = 0; t < 13; ++t) {
      st[t] = __builtin_amdgcn_mfma_f32_16x16x32_f16(ka0[t], qb0, zero4, 0, 0, 0);
      st[t] = __builtin_amdgcn_mfma_f32_16x16x32_f16(ka1[t], qb1, st[t], 0, 0, 0);
    }

    float mx = -1e30f;
#pragma unroll
    for (int t = 0; t < 13; ++t)
#pragma unroll
      for (int j = 0; j < 4; ++j) {
        int key = t * 16 + g * 4 + j;
        if (key >= 197) st[t][j] = -1e30f;
        mx = fmaxf(mx, st[t][j]);
      }
    mx = fmaxf(mx, __shfl_xor(mx, 16));
    mx = fmaxf(mx, __shfl_xor(mx, 32));
    float l = 0.f;
#pragma unroll
    for (int t = 0; t < 13; ++t)
#pragma unroll
      for (int j = 0; j < 4; ++j) {
        float p = __expf(st[t][j] - mx);
        st[t][j] = p;
        l += p;
      }
    l += __shfl_xor(l, 16);
    l += __shfl_xor(l, 32);
    const float inv = 1.f / l;

#pragma unroll
    for (int t = 0; t < 13; ++t) {
      half4_t hp;
#pragma unroll
      for (int j = 0; j < 4; ++j) hp[j] = (_Float16)(st[t][j] * inv);
      *(half4_t*)(Pw + lc * 232 + t * 16 + g * 4) = hp;
    }

    f32x4 o[4];
#pragma unroll
    for (int dt = 0; dt < 4; ++dt) o[dt] = zero4;
#pragma unroll
    for (int c = 0; c < 7; ++c) {
      half8_t pa = *(const half8_t*)(Pw + lc * 232 + c * 32 + g * 8);
#pragma unroll
      for (int dt = 0; dt < 4; ++dt) {
        half8_t vb = *(const half8_t*)(VT + (dt * 16 + lc) * 232 + c * 32 + g * 8);
        o[dt] = __builtin_amdgcn_mfma_f32_16x16x32_f16(pa, vb, o[dt], 0, 0, 0);
      }
    }

#pragma unroll
    for (int dt = 0; dt < 4; ++dt)
#pragma unroll
      for (int j = 0; j < 4; ++j) {
        int q = qt * 16 + g * 4 + j;
        if (q < NP_) {
          int tok = 1 + fi * NP_ + q;
          attnh[((size_t)(b * SEQ_) + tok) * DIM_ + h * DH_ + dt * 16 + lc] =
              (_Float16)o[dt][j];
        }
      }
  }
}

// ---------------------------------------------------------------------------
extern "C" void kernel_launch(void* const* d_in, const int* in_sizes, int n_in,
                              void* d_out, int out_size, void* d_ws, size_t ws_size,
                              hipStream_t stream) {
  (void)in_sizes; (void)n_in; (void)out_size; (void)ws_size;
  const float* x    = (const float*)d_in[0];
  const float* wqkv = (const float*)d_in[1];
  const float* wout = (const float*)d_in[2];
  const float* bout = (const float*)d_in[3];
  char* ws = (char*)d_ws;
  _Float16* xh    = (_Float16*)(ws + XH_OFF);
  _Float16* wqkvT = (_Float16*)(ws + WQKVT_OFF);
  _Float16* woutT = (_Float16*)(ws + WOUTT_OFF);
  _Float16* qh    = (_Float16*)(ws + QH_OFF);
  _Float16* kh    = (_Float16*)(ws + KH_OFF);
  _Float16* vh    = (_Float16*)(ws + VH_OFF);
  _Float16* attnh = (_Float16*)(ws + ATTNH_OFF);
  float* out = (float*)d_out;

  convert_x_kernel<<<2048, 256, 0, stream>>>(x, xh);
  {
    dim3 g(DIM_ / 32, NQKV_ / 32);
    transpose_conv_kernel<<<g, 256, 0, stream>>>(wqkv, wqkvT, DIM_, NQKV_);
  }
  {
    dim3 g(DIM_ / 32, DIM_ / 32);
    transpose_conv_kernel<<<g, 256, 0, stream>>>(wout, woutT, DIM_, DIM_);
  }

  qkv_gemm_kernel<<<197 * 12, 256, 0, stream>>>(xh, wqkvT, qh, kh, vh);

  cls_attn_kernel<<<BH_, 1024, 0, stream>>>(qh, kh, vh, attnh);
  frame_attn_kernel<<<BH_ * F_, 256, 0, stream>>>(qh, kh, vh, attnh);

  out_gemm_kernel<<<197 * 4, 256, 0, stream>>>(attnh, woutT, bout, out);
}